// Round 8
// baseline (727.541 us; speedup 1.0000x reference)
//
#include <hip/hip_runtime.h>
#include <cstdint>
#include <cstddef>

typedef __attribute__((ext_vector_type(8))) short short8;
typedef __attribute__((ext_vector_type(4))) float f32x4;

// ---------------- bf16 split helpers (round-to-nearest-even) ----------------

__device__ inline unsigned short f2bf(float f) {
    unsigned int u = __float_as_uint(f);
    u = u + 0x7fff + ((u >> 16) & 1);
    return (unsigned short)(u >> 16);
}
__device__ inline float bf2f(unsigned short h) {
    return __uint_as_float(((unsigned int)h) << 16);
}
__device__ inline void split2(float v, unsigned short& hi, unsigned short& lo) {
    hi = f2bf(v);
    lo = f2bf(v - bf2f(hi));
}

// ---------------- preprocessing kernels ----------------

__global__ void zero_ints(int* p, int n) {
    int i = blockIdx.x * 256 + threadIdx.x;
    if (i < n) p[i] = 0;
}

__global__ void count_deg(const int* __restrict__ dst, int* __restrict__ cnt, int E) {
    int i = blockIdx.x * 256 + threadIdx.x;
    if (i < E) atomicAdd(&cnt[dst[i]], 1);
}

__global__ void compute_dis(const int* __restrict__ cnt, float* __restrict__ dis, int N) {
    int i = blockIdx.x * 256 + threadIdx.x;
    if (i < N) dis[i] = rsqrtf((float)cnt[i] + 1.0f);
}

// ---------------- 3-phase parallel exclusive scan over cnt -> rp, cursor ----------------

__global__ __launch_bounds__(256) void scan_block_sums(const int* __restrict__ cnt,
                                                       int* __restrict__ partials, int N) {
    __shared__ int s[256];
    int t = threadIdx.x;
    int base = blockIdx.x * 1024 + t * 4;
    int v = 0;
    if (base + 3 < N) {
        int4 d = *(const int4*)&cnt[base];
        v = d.x + d.y + d.z + d.w;
    } else {
        for (int j = 0; j < 4; ++j) if (base + j < N) v += cnt[base + j];
    }
    s[t] = v;
    __syncthreads();
    for (int off = 128; off > 0; off >>= 1) {
        if (t < off) s[t] += s[t + off];
        __syncthreads();
    }
    if (t == 0) partials[blockIdx.x] = s[0];
}

__global__ __launch_bounds__(256) void scan_partials(int* __restrict__ partials, int nb,
                                                     int* __restrict__ rp, int N) {
    __shared__ int s[256];
    int t = threadIdx.x;
    int base = t * 4;
    int v0 = 0, v1 = 0, v2 = 0, v3 = 0;
    if (base < nb)     v0 = partials[base];
    if (base + 1 < nb) v1 = partials[base + 1];
    if (base + 2 < nb) v2 = partials[base + 2];
    if (base + 3 < nb) v3 = partials[base + 3];
    s[t] = v0 + v1 + v2 + v3;
    __syncthreads();
    for (int off = 1; off < 256; off <<= 1) {
        int v = s[t];
        int u = (t >= off) ? s[t - off] : 0;
        __syncthreads();
        s[t] = v + u;
        __syncthreads();
    }
    int run = (t == 0) ? 0 : s[t - 1];
    if (base < nb)     { partials[base] = run;     run += v0; }
    if (base + 1 < nb) { partials[base + 1] = run; run += v1; }
    if (base + 2 < nb) { partials[base + 2] = run; run += v2; }
    if (base + 3 < nb) { partials[base + 3] = run; run += v3; }
    if (t == 255) rp[N] = s[255];
}

__global__ __launch_bounds__(256) void scan_write(const int* __restrict__ cnt,
                                                  const int* __restrict__ partials,
                                                  int* __restrict__ rp,
                                                  int* __restrict__ cursor, int N) {
    __shared__ int s[256];
    int t = threadIdx.x;
    int base = blockIdx.x * 1024 + t * 4;
    int v0 = 0, v1 = 0, v2 = 0, v3 = 0;
    if (base + 3 < N) {
        int4 d = *(const int4*)&cnt[base];
        v0 = d.x; v1 = d.y; v2 = d.z; v3 = d.w;
    } else {
        if (base < N)     v0 = cnt[base];
        if (base + 1 < N) v1 = cnt[base + 1];
        if (base + 2 < N) v2 = cnt[base + 2];
    }
    s[t] = v0 + v1 + v2 + v3;
    __syncthreads();
    for (int off = 1; off < 256; off <<= 1) {
        int v = s[t];
        int u = (t >= off) ? s[t - off] : 0;
        __syncthreads();
        s[t] = v + u;
        __syncthreads();
    }
    int run = partials[blockIdx.x] + ((t == 0) ? 0 : s[t - 1]);
    int4 o;
    o.x = run; run += v0;
    o.y = run; run += v1;
    o.z = run; run += v2;
    o.w = run; run += v3;
    if (base + 3 < N) {
        *(int4*)&rp[base] = o;
        *(int4*)&cursor[base] = o;
    } else {
        if (base < N)     { rp[base] = o.x;     cursor[base] = o.x; }
        if (base + 1 < N) { rp[base + 1] = o.y; cursor[base + 1] = o.y; }
        if (base + 2 < N) { rp[base + 2] = o.z; cursor[base + 2] = o.z; }
    }
}

// edata[pos] = (src, bitcast(norm)) — one 8B record per edge
__global__ void scatter_edges(const int* __restrict__ src, const int* __restrict__ dstv,
                              const float* __restrict__ dis, int* __restrict__ cursor,
                              int2* __restrict__ edata, int E) {
    int i = blockIdx.x * 256 + threadIdx.x;
    if (i < E) {
        int s = src[i], d = dstv[i];
        int pos = atomicAdd(&cursor[d], 1);
        edata[pos] = make_int2(s, __float_as_int(dis[s] * dis[d]));
    }
}

__global__ void build_h0(const float* __restrict__ x, const float* __restrict__ xm,
                         float* __restrict__ h0, int N) {
    int i = blockIdx.x * 256 + threadIdx.x;
    if (i < N * 16) {
        int node = i >> 4, f = i & 15;
        h0[i] = (f < 8) ? x[node * 10 + f] : xm[node * 10 + f - 8];
    }
}

// ---------------- W split into MFMA B-fragment order ----------------
// For layer l (0..3 = Wh[l], 4 = Wr1): entry g = l*16384 + ((chunk*8+tc)*64+lane)*8+j
// holds W[k][n], k = chunk*32 + (lane>>4)*8 + j, n = tc*16 + (lane&15).

__global__ __launch_bounds__(256) void wsplit_kernel(const float* __restrict__ Wh,
                                                     const float* __restrict__ Wr1,
                                                     unsigned short* __restrict__ whi,
                                                     unsigned short* __restrict__ wlo) {
    int g = blockIdx.x * 256 + threadIdx.x;   // 5*16384 entries
    int l = g >> 14;
    int idx = g & 16383;
    int j = idx & 7;
    int lane = (idx >> 3) & 63;
    int tcchunk = idx >> 9;                   // 0..31
    int tc = tcchunk & 7, chunk = tcchunk >> 3;
    int k = chunk * 32 + (lane >> 4) * 8 + j;
    int n = tc * 16 + (lane & 15);
    float v = (l < 4) ? Wh[l * 16384 + k * 128 + n] : Wr1[k * 128 + n];
    unsigned short hi, lo;
    split2(v, hi, lo);
    whi[g] = hi;
    wlo[g] = lo;
}

// ---------------- aggregation, 128-wide: 32 lanes/node, float4 gathers, 4-edge unroll ----------------
// emits split-bf16 (ah, al)

__global__ __launch_bounds__(256) void agg128split_kernel(const float* __restrict__ h,
                                                          const int* __restrict__ rp,
                                                          const int2* __restrict__ edata,
                                                          const float* __restrict__ dis,
                                                          unsigned short* __restrict__ oah,
                                                          unsigned short* __restrict__ oal,
                                                          int N) {
    int node = blockIdx.x * 8 + (threadIdx.x >> 5);
    int lane = threadIdx.x & 31;
    if (node >= N) return;
    int beg = rp[node], end = rp[node + 1];
    float di = dis[node];
    const float4* h4 = (const float4*)h;
    float4 self = h4[(size_t)node * 32 + lane];
    float sc = di * di;
    float a0 = self.x * sc, a1 = self.y * sc, a2 = self.z * sc, a3 = self.w * sc;
    int e = beg;
    for (; e + 4 <= end; e += 4) {
        int2 e0 = edata[e], e1 = edata[e + 1], e2 = edata[e + 2], e3 = edata[e + 3];
        float4 v0 = h4[(size_t)e0.x * 32 + lane];
        float4 v1 = h4[(size_t)e1.x * 32 + lane];
        float4 v2 = h4[(size_t)e2.x * 32 + lane];
        float4 v3 = h4[(size_t)e3.x * 32 + lane];
        float n0 = __int_as_float(e0.y), n1 = __int_as_float(e1.y);
        float n2 = __int_as_float(e2.y), n3 = __int_as_float(e3.y);
        a0 += v0.x * n0; a1 += v0.y * n0; a2 += v0.z * n0; a3 += v0.w * n0;
        a0 += v1.x * n1; a1 += v1.y * n1; a2 += v1.z * n1; a3 += v1.w * n1;
        a0 += v2.x * n2; a1 += v2.y * n2; a2 += v2.z * n2; a3 += v2.w * n2;
        a0 += v3.x * n3; a1 += v3.y * n3; a2 += v3.z * n3; a3 += v3.w * n3;
    }
    for (; e < end; ++e) {
        int2 ee = edata[e];
        float4 v = h4[(size_t)ee.x * 32 + lane];
        float nr = __int_as_float(ee.y);
        a0 += v.x * nr; a1 += v.y * nr; a2 += v.z * nr; a3 += v.w * nr;
    }
    ushort4 hh, ll;
    split2(a0, hh.x, ll.x);
    split2(a1, hh.y, ll.y);
    split2(a2, hh.z, ll.z);
    split2(a3, hh.w, ll.w);
    *(ushort4*)&oah[(size_t)node * 128 + lane * 4] = hh;
    *(ushort4*)&oal[(size_t)node * 128 + lane * 4] = ll;
}

// ---------------- aggregation, 16-wide (layer 0): fp32 out ----------------

__global__ __launch_bounds__(256) void agg16_kernel(const float* __restrict__ h,
                                                    const int* __restrict__ rp,
                                                    const int2* __restrict__ edata,
                                                    const float* __restrict__ dis,
                                                    float* __restrict__ out, int N) {
    int node = blockIdx.x * 16 + (threadIdx.x >> 4);
    int t = threadIdx.x & 15;
    if (node >= N) return;
    int beg = rp[node], end = rp[node + 1];
    float di = dis[node];
    float acc = h[(size_t)node * 16 + t] * (di * di);
    int e = beg;
    for (; e + 4 <= end; e += 4) {
        int2 e0 = edata[e], e1 = edata[e + 1], e2 = edata[e + 2], e3 = edata[e + 3];
        float v0 = h[(size_t)e0.x * 16 + t];
        float v1 = h[(size_t)e1.x * 16 + t];
        float v2 = h[(size_t)e2.x * 16 + t];
        float v3 = h[(size_t)e3.x * 16 + t];
        acc += v0 * __int_as_float(e0.y);
        acc += v1 * __int_as_float(e1.y);
        acc += v2 * __int_as_float(e2.y);
        acc += v3 * __int_as_float(e3.y);
    }
    for (; e < end; ++e) {
        int2 ee = edata[e];
        acc += h[(size_t)ee.x * 16 + t] * __int_as_float(ee.y);
    }
    out[(size_t)node * 16 + t] = acc;
}

// ---------------- layer-0 GEMM (K=16): VALU fp32, W in LDS ----------------

template <int K, bool RELU_OUT>
__global__ __launch_bounds__(256, 4) void gemm_kernel(const float* __restrict__ A,
                                                      const float* __restrict__ W,
                                                      const float* __restrict__ bias,
                                                      float* __restrict__ out, int N) {
    constexpr int KS = (K < 64) ? K : 64;
    __shared__ float sW[KS * 128];
    int t = threadIdx.x;
    int row0 = blockIdx.x * 64;
    int cg = t & 31, rg = t >> 5;
    int c0 = cg * 4;
    int r0 = row0 + rg * 8;

    const float* Ar[8];
    #pragma unroll
    for (int i = 0; i < 8; ++i) {
        int rr = min(r0 + i, N - 1);
        Ar[i] = A + (size_t)rr * K;
    }

    float4 acc[8];
    #pragma unroll
    for (int i = 0; i < 8; ++i) acc[i] = make_float4(0.f, 0.f, 0.f, 0.f);

    for (int ks = 0; ks < K; ks += KS) {
        if (ks) __syncthreads();
        for (int i = t * 4; i < KS * 128; i += 1024) {
            *(float4*)&sW[i] = *(const float4*)&W[ks * 128 + i];
        }
        __syncthreads();

        for (int kk = 0; kk < KS; kk += 4) {
            float4 a[8];
            #pragma unroll
            for (int i = 0; i < 8; ++i) a[i] = *(const float4*)&Ar[i][ks + kk];
            float4 w[4];
            #pragma unroll
            for (int j = 0; j < 4; ++j) w[j] = *(const float4*)&sW[(kk + j) * 128 + c0];
            #pragma unroll
            for (int i = 0; i < 8; ++i) {
                const float* ap = (const float*)&a[i];
                #pragma unroll
                for (int j = 0; j < 4; ++j) {
                    float av = ap[j];
                    acc[i].x += av * w[j].x;
                    acc[i].y += av * w[j].y;
                    acc[i].z += av * w[j].z;
                    acc[i].w += av * w[j].w;
                }
            }
        }
    }

    float4 bb = *(const float4*)&bias[c0];
    #pragma unroll
    for (int i = 0; i < 8; ++i) {
        int row = r0 + i;
        if (row < N) {
            float4 v;
            v.x = acc[i].x + bb.x; v.y = acc[i].y + bb.y;
            v.z = acc[i].z + bb.z; v.w = acc[i].w + bb.w;
            if (RELU_OUT) {
                v.x = fmaxf(v.x, 0.f); v.y = fmaxf(v.y, 0.f);
                v.z = fmaxf(v.z, 0.f); v.w = fmaxf(v.w, 0.f);
            }
            *(float4*)&out[(size_t)row * 128 + c0] = v;
        }
    }
}

// ---------------- MFMA GEMM: C[N x 128] = (ah+al)[N x 128] @ W[128 x 128] + bias ----------------
// bf16x3: C = ah*wh + al*wh + ah*wl (al*wl dropped, ~2^-18 relative).

template <bool RELU_OUT>
__global__ __launch_bounds__(256) void mfma_gemm_kernel(
    const unsigned short* __restrict__ ah, const unsigned short* __restrict__ al,
    const unsigned short* __restrict__ whi, const unsigned short* __restrict__ wlo,
    const float* __restrict__ bias, float* __restrict__ out, int N) {
    int t = threadIdx.x;
    int wave = t >> 6, lane = t & 63;
    int m = lane & 15, q = lane >> 4;
    int r0 = blockIdx.x * 64 + wave * 16;
    int arow = min(r0 + m, N - 1);
    const unsigned short* ap = ah + (size_t)arow * 128 + q * 8;
    const unsigned short* lp = al + (size_t)arow * 128 + q * 8;

    f32x4 acc[8];
    #pragma unroll
    for (int i = 0; i < 8; ++i) acc[i] = (f32x4)(0.f);

    #pragma unroll
    for (int chunk = 0; chunk < 4; ++chunk) {
        short8 af = *(const short8*)(ap + chunk * 32);
        short8 lf = *(const short8*)(lp + chunk * 32);
        const unsigned short* wb = whi + (size_t)(chunk * 8) * 512 + lane * 8;
        const unsigned short* wc = wlo + (size_t)(chunk * 8) * 512 + lane * 8;
        #pragma unroll
        for (int tc = 0; tc < 8; ++tc) {
            short8 wh = *(const short8*)(wb + tc * 512);
            short8 wl = *(const short8*)(wc + tc * 512);
            acc[tc] = __builtin_amdgcn_mfma_f32_16x16x32_bf16(af, wh, acc[tc], 0, 0, 0);
            acc[tc] = __builtin_amdgcn_mfma_f32_16x16x32_bf16(lf, wh, acc[tc], 0, 0, 0);
            acc[tc] = __builtin_amdgcn_mfma_f32_16x16x32_bf16(af, wl, acc[tc], 0, 0, 0);
        }
    }

    // C/D layout: col = lane&15, row = (lane>>4)*4 + reg  [m89/m91-verified]
    int crow = r0 + q * 4;
    #pragma unroll
    for (int tc = 0; tc < 8; ++tc) {
        int col = tc * 16 + m;
        float b = bias[col];
        #pragma unroll
        for (int r = 0; r < 4; ++r) {
            int rr = crow + r;
            if (rr < N) {
                float v = acc[tc][r] + b;
                if (RELU_OUT) v = fmaxf(v, 0.f);
                out[(size_t)rr * 128 + col] = v;
            }
        }
    }
}

// ---------------- fused head: pred = relu((ah+al) @ Wr1 + br1) @ Wr2 + br2 ----------------

__global__ __launch_bounds__(256) void mfma_head_kernel(
    const unsigned short* __restrict__ ah, const unsigned short* __restrict__ al,
    const unsigned short* __restrict__ whi, const unsigned short* __restrict__ wlo,
    const float* __restrict__ br1, const float* __restrict__ Wr2,
    const float* __restrict__ br2, float* __restrict__ pred, int N) {
    int t = threadIdx.x;
    int wave = t >> 6, lane = t & 63;
    int m = lane & 15, q = lane >> 4;
    int r0 = blockIdx.x * 64 + wave * 16;
    int arow = min(r0 + m, N - 1);
    const unsigned short* ap = ah + (size_t)arow * 128 + q * 8;
    const unsigned short* lp = al + (size_t)arow * 128 + q * 8;

    f32x4 acc[8];
    #pragma unroll
    for (int i = 0; i < 8; ++i) acc[i] = (f32x4)(0.f);

    #pragma unroll
    for (int chunk = 0; chunk < 4; ++chunk) {
        short8 af = *(const short8*)(ap + chunk * 32);
        short8 lf = *(const short8*)(lp + chunk * 32);
        const unsigned short* wb = whi + (size_t)(chunk * 8) * 512 + lane * 8;
        const unsigned short* wc = wlo + (size_t)(chunk * 8) * 512 + lane * 8;
        #pragma unroll
        for (int tc = 0; tc < 8; ++tc) {
            short8 wh = *(const short8*)(wb + tc * 512);
            short8 wl = *(const short8*)(wc + tc * 512);
            acc[tc] = __builtin_amdgcn_mfma_f32_16x16x32_bf16(af, wh, acc[tc], 0, 0, 0);
            acc[tc] = __builtin_amdgcn_mfma_f32_16x16x32_bf16(lf, wh, acc[tc], 0, 0, 0);
            acc[tc] = __builtin_amdgcn_mfma_f32_16x16x32_bf16(af, wl, acc[tc], 0, 0, 0);
        }
    }

    float p0[4] = {0.f, 0.f, 0.f, 0.f};
    float p1[4] = {0.f, 0.f, 0.f, 0.f};
    float p2[4] = {0.f, 0.f, 0.f, 0.f};
    #pragma unroll
    for (int tc = 0; tc < 8; ++tc) {
        int col = tc * 16 + m;
        float b1 = br1[col];
        float w0 = Wr2[col * 3 + 0], w1 = Wr2[col * 3 + 1], w2 = Wr2[col * 3 + 2];
        #pragma unroll
        for (int r = 0; r < 4; ++r) {
            float hv = fmaxf(acc[tc][r] + b1, 0.f);
            p0[r] += hv * w0;
            p1[r] += hv * w1;
            p2[r] += hv * w2;
        }
    }
    #pragma unroll
    for (int mask = 1; mask < 16; mask <<= 1) {
        #pragma unroll
        for (int r = 0; r < 4; ++r) {
            p0[r] += __shfl_xor(p0[r], mask);
            p1[r] += __shfl_xor(p1[r], mask);
            p2[r] += __shfl_xor(p2[r], mask);
        }
    }
    if (m == 0) {
        int crow = r0 + q * 4;
        #pragma unroll
        for (int r = 0; r < 4; ++r) {
            int rr = crow + r;
            if (rr < N) {
                pred[(size_t)rr * 3 + 0] = p0[r] + br2[0];
                pred[(size_t)rr * 3 + 1] = p1[r] + br2[1];
                pred[(size_t)rr * 3 + 2] = p2[r] + br2[2];
            }
        }
    }
}

// ---------------- relu + split pass: emb (fp32) -> (ah, al) bf16 pairs ----------------

__global__ __launch_bounds__(256) void relusplit_kernel(const float* __restrict__ in,
                                                        unsigned short* __restrict__ ah,
                                                        unsigned short* __restrict__ al,
                                                        int total) {
    int i = (blockIdx.x * 256 + threadIdx.x) * 4;
    if (i >= total) return;
    float4 v = *(const float4*)&in[i];
    v.x = fmaxf(v.x, 0.f); v.y = fmaxf(v.y, 0.f);
    v.z = fmaxf(v.z, 0.f); v.w = fmaxf(v.w, 0.f);
    ushort4 h, l;
    split2(v.x, h.x, l.x);
    split2(v.y, h.y, l.y);
    split2(v.z, h.z, l.z);
    split2(v.w, h.w, l.w);
    *(ushort4*)&ah[i] = h;
    *(ushort4*)&al[i] = l;
}

// ---------------- launch ----------------

extern "C" void kernel_launch(void* const* d_in, const int* in_sizes, int n_in,
                              void* d_out, int out_size, void* d_ws, size_t ws_size,
                              hipStream_t stream) {
    const float* x   = (const float*)d_in[0];
    const float* xm  = (const float*)d_in[1];
    const int*   ei  = (const int*)d_in[2];
    const float* W0  = (const float*)d_in[3];
    const float* b0  = (const float*)d_in[4];
    const float* Wh  = (const float*)d_in[5];
    const float* bh  = (const float*)d_in[6];
    const float* Wr1 = (const float*)d_in[7];
    const float* br1 = (const float*)d_in[8];
    const float* Wr2 = (const float*)d_in[9];
    const float* br2 = (const float*)d_in[10];
    float* out = (float*)d_out;

    int N = in_sizes[0] / 10;
    int E = in_sizes[2] / 2;
    const int* src = ei;
    const int* dst = ei + E;

    float* emb_out  = out;                   // N x 128 (final GCN layer writes here)
    float* pred_out = out + (size_t)N * 128; // N x 3

    char* ws = (char*)d_ws;
    size_t off = 0;
    auto alloc = [&](size_t bytes) -> void* {
        void* p = ws + off;
        off += (bytes + 255) & ~(size_t)255;
        return p;
    };
    // regionA: split activations ah[N*128] | al[N*128] (51.2 MB).
    // h0 (6.4 MB) and agg16out (6.4 MB) alias its head — both dead before first split write.
    unsigned short* ahb = (unsigned short*)alloc((size_t)N * 128 * 2 * 2);
    unsigned short* alb = ahb + (size_t)N * 128;
    float* h0       = (float*)ahb;
    float* agg16out = (float*)((char*)ahb + (size_t)N * 16 * 4);
    int*   cnt      = (int*)alloc((size_t)N * 4);
    float* dis      = (float*)alloc((size_t)N * 4);
    int*   rp       = (int*)alloc((size_t)(N + 1) * 4);
    int*   cursor   = (int*)alloc((size_t)N * 4);
    int2*  edata    = (int2*)alloc((size_t)E * 8);
    int*   partials = (int*)alloc((size_t)1024 * 4);
    unsigned short* whi = (unsigned short*)alloc((size_t)5 * 16384 * 2);
    unsigned short* wlo = (unsigned short*)alloc((size_t)5 * 16384 * 2);
    // hbuf: fp32 h ping buffer. Prefer ws (d_out showed 4x write amplification on
    // every kernel that stored to it); if ws can't fit it, fall back to the
    // emb region of d_out (the R5-proven layout — correct either way).
    float* hbuf_ws = (float*)alloc((size_t)N * 128 * 4);
    float* hbuf = (off <= ws_size) ? hbuf_ws : emb_out;

    int gN = (N + 255) / 256, gE = (E + 255) / 256;
    int gRows = (N + 63) / 64;
    int nScanBlocks = (N + 1023) / 1024;

    zero_ints<<<gN, 256, 0, stream>>>(cnt, N);
    count_deg<<<gE, 256, 0, stream>>>(dst, cnt, E);
    compute_dis<<<gN, 256, 0, stream>>>(cnt, dis, N);
    scan_block_sums<<<nScanBlocks, 256, 0, stream>>>(cnt, partials, N);
    scan_partials<<<1, 256, 0, stream>>>(partials, nScanBlocks, rp, N);
    scan_write<<<nScanBlocks, 256, 0, stream>>>(cnt, partials, rp, cursor, N);
    scatter_edges<<<gE, 256, 0, stream>>>(src, dst, dis, cursor, edata, E);
    build_h0<<<(N * 16 + 255) / 256, 256, 0, stream>>>(x, xm, h0, N);
    wsplit_kernel<<<5 * 16384 / 256, 256, 0, stream>>>(Wh, Wr1, whi, wlo);

    // layer 0: agg h0 (16-wide) -> VALU GEMM 16->128 with relu -> hbuf
    agg16_kernel<<<(N + 15) / 16, 256, 0, stream>>>(h0, rp, edata, dis, agg16out, N);
    gemm_kernel<16, true><<<gRows, 256, 0, stream>>>(agg16out, W0, b0, hbuf, N);

    // hidden layers: agg 128-wide (split out) -> bf16x3 MFMA GEMM
    for (int l = 0; l < 4; ++l) {
        agg128split_kernel<<<(N + 7) / 8, 256, 0, stream>>>(hbuf, rp, edata, dis, ahb, alb, N);
        const unsigned short* wh_l = whi + (size_t)l * 16384;
        const unsigned short* wl_l = wlo + (size_t)l * 16384;
        if (l < 3)
            mfma_gemm_kernel<true><<<gRows, 256, 0, stream>>>(
                ahb, alb, wh_l, wl_l, bh + (size_t)l * 128, hbuf, N);
        else
            // last GCN layer: pre-relu emb straight into d_out (required output)
            mfma_gemm_kernel<false><<<gRows, 256, 0, stream>>>(
                ahb, alb, wh_l, wl_l, bh + (size_t)l * 128, emb_out, N);
    }

    // head: relu(emb) -> split; fused (Wr1 + relu + Wr2) MFMA kernel -> pred
    relusplit_kernel<<<(N * 128 / 4 + 255) / 256, 256, 0, stream>>>(emb_out, ahb, alb, N * 128);
    mfma_head_kernel<<<gRows, 256, 0, stream>>>(ahb, alb, whi + (size_t)4 * 16384,
                                                wlo + (size_t)4 * 16384, br1, Wr2, br2,
                                                pred_out, N);
}

// Round 9
// 619.239 us; speedup vs baseline: 1.1749x; 1.1749x over previous
//
#include <hip/hip_runtime.h>
#include <cstdint>
#include <cstddef>

typedef __attribute__((ext_vector_type(8))) short short8;
typedef __attribute__((ext_vector_type(4))) float f32x4;
typedef __attribute__((ext_vector_type(4))) _Float16 half4v;

// ---------------- bf16 split helpers (round-to-nearest-even) ----------------

__device__ inline unsigned short f2bf(float f) {
    unsigned int u = __float_as_uint(f);
    u = u + 0x7fff + ((u >> 16) & 1);
    return (unsigned short)(u >> 16);
}
__device__ inline float bf2f(unsigned short h) {
    return __uint_as_float(((unsigned int)h) << 16);
}
__device__ inline void split2(float v, unsigned short& hi, unsigned short& lo) {
    hi = f2bf(v);
    lo = f2bf(v - bf2f(hi));
}

// ---------------- preprocessing kernels ----------------

__global__ void zero_ints(int* p, int n) {
    int i = blockIdx.x * 256 + threadIdx.x;
    if (i < n) p[i] = 0;
}

__global__ void count_deg(const int* __restrict__ dst, int* __restrict__ cnt, int E) {
    int i = blockIdx.x * 256 + threadIdx.x;
    if (i < E) atomicAdd(&cnt[dst[i]], 1);
}

__global__ void compute_dis(const int* __restrict__ cnt, float* __restrict__ dis, int N) {
    int i = blockIdx.x * 256 + threadIdx.x;
    if (i < N) dis[i] = rsqrtf((float)cnt[i] + 1.0f);
}

// ---------------- 3-phase parallel exclusive scan over cnt -> rp, cursor ----------------

__global__ __launch_bounds__(256) void scan_block_sums(const int* __restrict__ cnt,
                                                       int* __restrict__ partials, int N) {
    __shared__ int s[256];
    int t = threadIdx.x;
    int base = blockIdx.x * 1024 + t * 4;
    int v = 0;
    if (base + 3 < N) {
        int4 d = *(const int4*)&cnt[base];
        v = d.x + d.y + d.z + d.w;
    } else {
        for (int j = 0; j < 4; ++j) if (base + j < N) v += cnt[base + j];
    }
    s[t] = v;
    __syncthreads();
    for (int off = 128; off > 0; off >>= 1) {
        if (t < off) s[t] += s[t + off];
        __syncthreads();
    }
    if (t == 0) partials[blockIdx.x] = s[0];
}

__global__ __launch_bounds__(256) void scan_partials(int* __restrict__ partials, int nb,
                                                     int* __restrict__ rp, int N) {
    __shared__ int s[256];
    int t = threadIdx.x;
    int base = t * 4;
    int v0 = 0, v1 = 0, v2 = 0, v3 = 0;
    if (base < nb)     v0 = partials[base];
    if (base + 1 < nb) v1 = partials[base + 1];
    if (base + 2 < nb) v2 = partials[base + 2];
    if (base + 3 < nb) v3 = partials[base + 3];
    s[t] = v0 + v1 + v2 + v3;
    __syncthreads();
    for (int off = 1; off < 256; off <<= 1) {
        int v = s[t];
        int u = (t >= off) ? s[t - off] : 0;
        __syncthreads();
        s[t] = v + u;
        __syncthreads();
    }
    int run = (t == 0) ? 0 : s[t - 1];
    if (base < nb)     { partials[base] = run;     run += v0; }
    if (base + 1 < nb) { partials[base + 1] = run; run += v1; }
    if (base + 2 < nb) { partials[base + 2] = run; run += v2; }
    if (base + 3 < nb) { partials[base + 3] = run; run += v3; }
    if (t == 255) rp[N] = s[255];
}

__global__ __launch_bounds__(256) void scan_write(const int* __restrict__ cnt,
                                                  const int* __restrict__ partials,
                                                  int* __restrict__ rp,
                                                  int* __restrict__ cursor, int N) {
    __shared__ int s[256];
    int t = threadIdx.x;
    int base = blockIdx.x * 1024 + t * 4;
    int v0 = 0, v1 = 0, v2 = 0, v3 = 0;
    if (base + 3 < N) {
        int4 d = *(const int4*)&cnt[base];
        v0 = d.x; v1 = d.y; v2 = d.z; v3 = d.w;
    } else {
        if (base < N)     v0 = cnt[base];
        if (base + 1 < N) v1 = cnt[base + 1];
        if (base + 2 < N) v2 = cnt[base + 2];
    }
    s[t] = v0 + v1 + v2 + v3;
    __syncthreads();
    for (int off = 1; off < 256; off <<= 1) {
        int v = s[t];
        int u = (t >= off) ? s[t - off] : 0;
        __syncthreads();
        s[t] = v + u;
        __syncthreads();
    }
    int run = partials[blockIdx.x] + ((t == 0) ? 0 : s[t - 1]);
    int4 o;
    o.x = run; run += v0;
    o.y = run; run += v1;
    o.z = run; run += v2;
    o.w = run; run += v3;
    if (base + 3 < N) {
        *(int4*)&rp[base] = o;
        *(int4*)&cursor[base] = o;
    } else {
        if (base < N)     { rp[base] = o.x;     cursor[base] = o.x; }
        if (base + 1 < N) { rp[base + 1] = o.y; cursor[base + 1] = o.y; }
        if (base + 2 < N) { rp[base + 2] = o.z; cursor[base + 2] = o.z; }
    }
}

// edata[pos] = (src, bitcast(norm)) — one 8B record per edge
__global__ void scatter_edges(const int* __restrict__ src, const int* __restrict__ dstv,
                              const float* __restrict__ dis, int* __restrict__ cursor,
                              int2* __restrict__ edata, int E) {
    int i = blockIdx.x * 256 + threadIdx.x;
    if (i < E) {
        int s = src[i], d = dstv[i];
        int pos = atomicAdd(&cursor[d], 1);
        edata[pos] = make_int2(s, __float_as_int(dis[s] * dis[d]));
    }
}

__global__ void build_h0(const float* __restrict__ x, const float* __restrict__ xm,
                         float* __restrict__ h0, int N) {
    int i = blockIdx.x * 256 + threadIdx.x;
    if (i < N * 16) {
        int node = i >> 4, f = i & 15;
        h0[i] = (f < 8) ? x[node * 10 + f] : xm[node * 10 + f - 8];
    }
}

// ---------------- W split into MFMA B-fragment order ----------------

__global__ __launch_bounds__(256) void wsplit_kernel(const float* __restrict__ Wh,
                                                     const float* __restrict__ Wr1,
                                                     unsigned short* __restrict__ whi,
                                                     unsigned short* __restrict__ wlo) {
    int g = blockIdx.x * 256 + threadIdx.x;   // 5*16384 entries
    int l = g >> 14;
    int idx = g & 16383;
    int j = idx & 7;
    int lane = (idx >> 3) & 63;
    int tcchunk = idx >> 9;                   // 0..31
    int tc = tcchunk & 7, chunk = tcchunk >> 3;
    int k = chunk * 32 + (lane >> 4) * 8 + j;
    int n = tc * 16 + (lane & 15);
    float v = (l < 4) ? Wh[l * 16384 + k * 128 + n] : Wr1[k * 128 + n];
    unsigned short hi, lo;
    split2(v, hi, lo);
    whi[g] = hi;
    wlo[g] = lo;
}

// ---------------- aggregation, 128-wide: 32 lanes/node, 4-edge unroll ----------------
// F16IN: gather half4 (8B/lane); else float4 (16B/lane). Emits split-bf16 (ah, al).

template <bool F16IN>
__global__ __launch_bounds__(256) void agg128split_kernel(const void* __restrict__ hin,
                                                          const int* __restrict__ rp,
                                                          const int2* __restrict__ edata,
                                                          const float* __restrict__ dis,
                                                          unsigned short* __restrict__ oah,
                                                          unsigned short* __restrict__ oal,
                                                          int N) {
    int node = blockIdx.x * 8 + (threadIdx.x >> 5);
    int lane = threadIdx.x & 31;
    if (node >= N) return;
    int beg = rp[node], end = rp[node + 1];
    float di = dis[node];
    float sc = di * di;
    float a0, a1, a2, a3;
    if (F16IN) {
        const half4v* h4 = (const half4v*)hin;
        half4v self = h4[(size_t)node * 32 + lane];
        a0 = (float)self[0] * sc; a1 = (float)self[1] * sc;
        a2 = (float)self[2] * sc; a3 = (float)self[3] * sc;
        int e = beg;
        for (; e + 4 <= end; e += 4) {
            int2 e0 = edata[e], e1 = edata[e + 1], e2 = edata[e + 2], e3 = edata[e + 3];
            half4v v0 = h4[(size_t)e0.x * 32 + lane];
            half4v v1 = h4[(size_t)e1.x * 32 + lane];
            half4v v2 = h4[(size_t)e2.x * 32 + lane];
            half4v v3 = h4[(size_t)e3.x * 32 + lane];
            float n0 = __int_as_float(e0.y), n1 = __int_as_float(e1.y);
            float n2 = __int_as_float(e2.y), n3 = __int_as_float(e3.y);
            a0 += (float)v0[0] * n0; a1 += (float)v0[1] * n0; a2 += (float)v0[2] * n0; a3 += (float)v0[3] * n0;
            a0 += (float)v1[0] * n1; a1 += (float)v1[1] * n1; a2 += (float)v1[2] * n1; a3 += (float)v1[3] * n1;
            a0 += (float)v2[0] * n2; a1 += (float)v2[1] * n2; a2 += (float)v2[2] * n2; a3 += (float)v2[3] * n2;
            a0 += (float)v3[0] * n3; a1 += (float)v3[1] * n3; a2 += (float)v3[2] * n3; a3 += (float)v3[3] * n3;
        }
        for (; e < end; ++e) {
            int2 ee = edata[e];
            half4v v = h4[(size_t)ee.x * 32 + lane];
            float nr = __int_as_float(ee.y);
            a0 += (float)v[0] * nr; a1 += (float)v[1] * nr; a2 += (float)v[2] * nr; a3 += (float)v[3] * nr;
        }
    } else {
        const float4* h4 = (const float4*)hin;
        float4 self = h4[(size_t)node * 32 + lane];
        a0 = self.x * sc; a1 = self.y * sc; a2 = self.z * sc; a3 = self.w * sc;
        int e = beg;
        for (; e + 4 <= end; e += 4) {
            int2 e0 = edata[e], e1 = edata[e + 1], e2 = edata[e + 2], e3 = edata[e + 3];
            float4 v0 = h4[(size_t)e0.x * 32 + lane];
            float4 v1 = h4[(size_t)e1.x * 32 + lane];
            float4 v2 = h4[(size_t)e2.x * 32 + lane];
            float4 v3 = h4[(size_t)e3.x * 32 + lane];
            float n0 = __int_as_float(e0.y), n1 = __int_as_float(e1.y);
            float n2 = __int_as_float(e2.y), n3 = __int_as_float(e3.y);
            a0 += v0.x * n0; a1 += v0.y * n0; a2 += v0.z * n0; a3 += v0.w * n0;
            a0 += v1.x * n1; a1 += v1.y * n1; a2 += v1.z * n1; a3 += v1.w * n1;
            a0 += v2.x * n2; a1 += v2.y * n2; a2 += v2.z * n2; a3 += v2.w * n2;
            a0 += v3.x * n3; a1 += v3.y * n3; a2 += v3.z * n3; a3 += v3.w * n3;
        }
        for (; e < end; ++e) {
            int2 ee = edata[e];
            float4 v = h4[(size_t)ee.x * 32 + lane];
            float nr = __int_as_float(ee.y);
            a0 += v.x * nr; a1 += v.y * nr; a2 += v.z * nr; a3 += v.w * nr;
        }
    }
    ushort4 hh, ll;
    split2(a0, hh.x, ll.x);
    split2(a1, hh.y, ll.y);
    split2(a2, hh.z, ll.z);
    split2(a3, hh.w, ll.w);
    *(ushort4*)&oah[(size_t)node * 128 + lane * 4] = hh;
    *(ushort4*)&oal[(size_t)node * 128 + lane * 4] = ll;
}

// ---------------- aggregation, 16-wide (layer 0): fp32 out ----------------

__global__ __launch_bounds__(256) void agg16_kernel(const float* __restrict__ h,
                                                    const int* __restrict__ rp,
                                                    const int2* __restrict__ edata,
                                                    const float* __restrict__ dis,
                                                    float* __restrict__ out, int N) {
    int node = blockIdx.x * 16 + (threadIdx.x >> 4);
    int t = threadIdx.x & 15;
    if (node >= N) return;
    int beg = rp[node], end = rp[node + 1];
    float di = dis[node];
    float acc = h[(size_t)node * 16 + t] * (di * di);
    int e = beg;
    for (; e + 4 <= end; e += 4) {
        int2 e0 = edata[e], e1 = edata[e + 1], e2 = edata[e + 2], e3 = edata[e + 3];
        float v0 = h[(size_t)e0.x * 16 + t];
        float v1 = h[(size_t)e1.x * 16 + t];
        float v2 = h[(size_t)e2.x * 16 + t];
        float v3 = h[(size_t)e3.x * 16 + t];
        acc += v0 * __int_as_float(e0.y);
        acc += v1 * __int_as_float(e1.y);
        acc += v2 * __int_as_float(e2.y);
        acc += v3 * __int_as_float(e3.y);
    }
    for (; e < end; ++e) {
        int2 ee = edata[e];
        acc += h[(size_t)ee.x * 16 + t] * __int_as_float(ee.y);
    }
    out[(size_t)node * 16 + t] = acc;
}

// ---------------- layer-0 GEMM (K=16): VALU fp32, W in LDS; OMODE 0=f32, 1=f16 ----------------

template <int K, int OMODE>
__global__ __launch_bounds__(256, 4) void gemm_kernel(const float* __restrict__ A,
                                                      const float* __restrict__ W,
                                                      const float* __restrict__ bias,
                                                      void* __restrict__ outv, int N) {
    constexpr int KS = (K < 64) ? K : 64;
    __shared__ float sW[KS * 128];
    int t = threadIdx.x;
    int row0 = blockIdx.x * 64;
    int cg = t & 31, rg = t >> 5;
    int c0 = cg * 4;
    int r0 = row0 + rg * 8;

    const float* Ar[8];
    #pragma unroll
    for (int i = 0; i < 8; ++i) {
        int rr = min(r0 + i, N - 1);
        Ar[i] = A + (size_t)rr * K;
    }

    float4 acc[8];
    #pragma unroll
    for (int i = 0; i < 8; ++i) acc[i] = make_float4(0.f, 0.f, 0.f, 0.f);

    for (int ks = 0; ks < K; ks += KS) {
        if (ks) __syncthreads();
        for (int i = t * 4; i < KS * 128; i += 1024) {
            *(float4*)&sW[i] = *(const float4*)&W[ks * 128 + i];
        }
        __syncthreads();

        for (int kk = 0; kk < KS; kk += 4) {
            float4 a[8];
            #pragma unroll
            for (int i = 0; i < 8; ++i) a[i] = *(const float4*)&Ar[i][ks + kk];
            float4 w[4];
            #pragma unroll
            for (int j = 0; j < 4; ++j) w[j] = *(const float4*)&sW[(kk + j) * 128 + c0];
            #pragma unroll
            for (int i = 0; i < 8; ++i) {
                const float* ap = (const float*)&a[i];
                #pragma unroll
                for (int j = 0; j < 4; ++j) {
                    float av = ap[j];
                    acc[i].x += av * w[j].x;
                    acc[i].y += av * w[j].y;
                    acc[i].z += av * w[j].z;
                    acc[i].w += av * w[j].w;
                }
            }
        }
    }

    float4 bb = *(const float4*)&bias[c0];
    #pragma unroll
    for (int i = 0; i < 8; ++i) {
        int row = r0 + i;
        if (row < N) {
            float4 v;
            v.x = fmaxf(acc[i].x + bb.x, 0.f); v.y = fmaxf(acc[i].y + bb.y, 0.f);
            v.z = fmaxf(acc[i].z + bb.z, 0.f); v.w = fmaxf(acc[i].w + bb.w, 0.f);
            if (OMODE == 1) {
                half4v o;
                o[0] = (_Float16)v.x; o[1] = (_Float16)v.y;
                o[2] = (_Float16)v.z; o[3] = (_Float16)v.w;
                *(half4v*)&((_Float16*)outv)[(size_t)row * 128 + c0] = o;
            } else {
                *(float4*)&((float*)outv)[(size_t)row * 128 + c0] = v;
            }
        }
    }
}

// ---------------- MFMA GEMM: C[N x 128] = (ah+al) @ W + bias ----------------
// bf16x3: C = ah*wh + al*wh + ah*wl. OMODE: 0=f32 plain, 1=f16, 2=f32 nontemporal.

template <bool RELU_OUT, int OMODE>
__global__ __launch_bounds__(256) void mfma_gemm_kernel(
    const unsigned short* __restrict__ ah, const unsigned short* __restrict__ al,
    const unsigned short* __restrict__ whi, const unsigned short* __restrict__ wlo,
    const float* __restrict__ bias, void* __restrict__ outv, int N) {
    int t = threadIdx.x;
    int wave = t >> 6, lane = t & 63;
    int m = lane & 15, q = lane >> 4;
    int r0 = blockIdx.x * 64 + wave * 16;
    int arow = min(r0 + m, N - 1);
    const unsigned short* ap = ah + (size_t)arow * 128 + q * 8;
    const unsigned short* lp = al + (size_t)arow * 128 + q * 8;

    f32x4 acc[8];
    #pragma unroll
    for (int i = 0; i < 8; ++i) acc[i] = (f32x4)(0.f);

    #pragma unroll
    for (int chunk = 0; chunk < 4; ++chunk) {
        short8 af = *(const short8*)(ap + chunk * 32);
        short8 lf = *(const short8*)(lp + chunk * 32);
        const unsigned short* wb = whi + (size_t)(chunk * 8) * 512 + lane * 8;
        const unsigned short* wc = wlo + (size_t)(chunk * 8) * 512 + lane * 8;
        #pragma unroll
        for (int tc = 0; tc < 8; ++tc) {
            short8 wh = *(const short8*)(wb + tc * 512);
            short8 wl = *(const short8*)(wc + tc * 512);
            acc[tc] = __builtin_amdgcn_mfma_f32_16x16x32_bf16(af, wh, acc[tc], 0, 0, 0);
            acc[tc] = __builtin_amdgcn_mfma_f32_16x16x32_bf16(lf, wh, acc[tc], 0, 0, 0);
            acc[tc] = __builtin_amdgcn_mfma_f32_16x16x32_bf16(af, wl, acc[tc], 0, 0, 0);
        }
    }

    // C/D layout: col = lane&15, row = (lane>>4)*4 + reg  [m89/m91-verified]
    int crow = r0 + q * 4;
    #pragma unroll
    for (int tc = 0; tc < 8; ++tc) {
        int col = tc * 16 + m;
        float b = bias[col];
        #pragma unroll
        for (int r = 0; r < 4; ++r) {
            int rr = crow + r;
            if (rr < N) {
                float v = acc[tc][r] + b;
                if (RELU_OUT) v = fmaxf(v, 0.f);
                size_t idx = (size_t)rr * 128 + col;
                if (OMODE == 1)      ((_Float16*)outv)[idx] = (_Float16)v;
                else if (OMODE == 2) __builtin_nontemporal_store(v, &((float*)outv)[idx]);
                else                 ((float*)outv)[idx] = v;
            }
        }
    }
}

// ---------------- fused head: pred = relu((ah+al) @ Wr1 + br1) @ Wr2 + br2 ----------------

__global__ __launch_bounds__(256) void mfma_head_kernel(
    const unsigned short* __restrict__ ah, const unsigned short* __restrict__ al,
    const unsigned short* __restrict__ whi, const unsigned short* __restrict__ wlo,
    const float* __restrict__ br1, const float* __restrict__ Wr2,
    const float* __restrict__ br2, float* __restrict__ pred, int N) {
    int t = threadIdx.x;
    int wave = t >> 6, lane = t & 63;
    int m = lane & 15, q = lane >> 4;
    int r0 = blockIdx.x * 64 + wave * 16;
    int arow = min(r0 + m, N - 1);
    const unsigned short* ap = ah + (size_t)arow * 128 + q * 8;
    const unsigned short* lp = al + (size_t)arow * 128 + q * 8;

    f32x4 acc[8];
    #pragma unroll
    for (int i = 0; i < 8; ++i) acc[i] = (f32x4)(0.f);

    #pragma unroll
    for (int chunk = 0; chunk < 4; ++chunk) {
        short8 af = *(const short8*)(ap + chunk * 32);
        short8 lf = *(const short8*)(lp + chunk * 32);
        const unsigned short* wb = whi + (size_t)(chunk * 8) * 512 + lane * 8;
        const unsigned short* wc = wlo + (size_t)(chunk * 8) * 512 + lane * 8;
        #pragma unroll
        for (int tc = 0; tc < 8; ++tc) {
            short8 wh = *(const short8*)(wb + tc * 512);
            short8 wl = *(const short8*)(wc + tc * 512);
            acc[tc] = __builtin_amdgcn_mfma_f32_16x16x32_bf16(af, wh, acc[tc], 0, 0, 0);
            acc[tc] = __builtin_amdgcn_mfma_f32_16x16x32_bf16(lf, wh, acc[tc], 0, 0, 0);
            acc[tc] = __builtin_amdgcn_mfma_f32_16x16x32_bf16(af, wl, acc[tc], 0, 0, 0);
        }
    }

    float p0[4] = {0.f, 0.f, 0.f, 0.f};
    float p1[4] = {0.f, 0.f, 0.f, 0.f};
    float p2[4] = {0.f, 0.f, 0.f, 0.f};
    #pragma unroll
    for (int tc = 0; tc < 8; ++tc) {
        int col = tc * 16 + m;
        float b1 = br1[col];
        float w0 = Wr2[col * 3 + 0], w1 = Wr2[col * 3 + 1], w2 = Wr2[col * 3 + 2];
        #pragma unroll
        for (int r = 0; r < 4; ++r) {
            float hv = fmaxf(acc[tc][r] + b1, 0.f);
            p0[r] += hv * w0;
            p1[r] += hv * w1;
            p2[r] += hv * w2;
        }
    }
    #pragma unroll
    for (int mask = 1; mask < 16; mask <<= 1) {
        #pragma unroll
        for (int r = 0; r < 4; ++r) {
            p0[r] += __shfl_xor(p0[r], mask);
            p1[r] += __shfl_xor(p1[r], mask);
            p2[r] += __shfl_xor(p2[r], mask);
        }
    }
    if (m == 0) {
        int crow = r0 + q * 4;
        #pragma unroll
        for (int r = 0; r < 4; ++r) {
            int rr = crow + r;
            if (rr < N) {
                __builtin_nontemporal_store(p0[r] + br2[0], &pred[(size_t)rr * 3 + 0]);
                __builtin_nontemporal_store(p1[r] + br2[1], &pred[(size_t)rr * 3 + 1]);
                __builtin_nontemporal_store(p2[r] + br2[2], &pred[(size_t)rr * 3 + 2]);
            }
        }
    }
}

// ---------------- relu + split pass: emb (fp32) -> (ah, al) bf16 pairs ----------------

__global__ __launch_bounds__(256) void relusplit_kernel(const float* __restrict__ in,
                                                        unsigned short* __restrict__ ah,
                                                        unsigned short* __restrict__ al,
                                                        int total) {
    int i = (blockIdx.x * 256 + threadIdx.x) * 4;
    if (i >= total) return;
    float4 v = *(const float4*)&in[i];
    v.x = fmaxf(v.x, 0.f); v.y = fmaxf(v.y, 0.f);
    v.z = fmaxf(v.z, 0.f); v.w = fmaxf(v.w, 0.f);
    ushort4 h, l;
    split2(v.x, h.x, l.x);
    split2(v.y, h.y, l.y);
    split2(v.z, h.z, l.z);
    split2(v.w, h.w, l.w);
    *(ushort4*)&ah[i] = h;
    *(ushort4*)&al[i] = l;
}

// ---------------- launch ----------------

extern "C" void kernel_launch(void* const* d_in, const int* in_sizes, int n_in,
                              void* d_out, int out_size, void* d_ws, size_t ws_size,
                              hipStream_t stream) {
    const float* x   = (const float*)d_in[0];
    const float* xm  = (const float*)d_in[1];
    const int*   ei  = (const int*)d_in[2];
    const float* W0  = (const float*)d_in[3];
    const float* b0  = (const float*)d_in[4];
    const float* Wh  = (const float*)d_in[5];
    const float* bh  = (const float*)d_in[6];
    const float* Wr1 = (const float*)d_in[7];
    const float* br1 = (const float*)d_in[8];
    const float* Wr2 = (const float*)d_in[9];
    const float* br2 = (const float*)d_in[10];
    float* out = (float*)d_out;

    int N = in_sizes[0] / 10;
    int E = in_sizes[2] / 2;
    const int* src = ei;
    const int* dst = ei + E;

    float* emb_out  = out;                   // N x 128 (final GCN layer writes here)
    float* pred_out = out + (size_t)N * 128; // N x 3

    char* ws = (char*)d_ws;
    size_t off = 0;
    auto alloc = [&](size_t bytes) -> void* {
        void* p = ws + off;
        off += (bytes + 255) & ~(size_t)255;
        return p;
    };
    // split activations ah|al (51.2 MB); h0 + agg16out alias its head (dead before 1st split write)
    unsigned short* ahb = (unsigned short*)alloc((size_t)N * 128 * 2 * 2);
    unsigned short* alb = ahb + (size_t)N * 128;
    float* h0       = (float*)ahb;
    float* agg16out = (float*)((char*)ahb + (size_t)N * 16 * 4);
    int*   cnt      = (int*)alloc((size_t)N * 4);
    float* dis      = (float*)alloc((size_t)N * 4);
    int*   rp       = (int*)alloc((size_t)(N + 1) * 4);
    int*   cursor   = (int*)alloc((size_t)N * 4);
    int2*  edata    = (int2*)alloc((size_t)E * 8);
    int*   partials = (int*)alloc((size_t)1024 * 4);
    unsigned short* whi = (unsigned short*)alloc((size_t)5 * 16384 * 2);
    unsigned short* wlo = (unsigned short*)alloc((size_t)5 * 16384 * 2);
    // xbuf: fp16 h ping buffer (25.6 MB). Fit in ws if possible (d_out stores
    // amplify ~4x); else fall back to fp32 X on the emb region (R5-proven).
    _Float16* xbuf_ws = (_Float16*)alloc((size_t)N * 128 * 2);
    bool fit = (off <= ws_size);

    int gN = (N + 255) / 256, gE = (E + 255) / 256;
    int gRows = (N + 63) / 64;
    int nScanBlocks = (N + 1023) / 1024;

    zero_ints<<<gN, 256, 0, stream>>>(cnt, N);
    count_deg<<<gE, 256, 0, stream>>>(dst, cnt, E);
    compute_dis<<<gN, 256, 0, stream>>>(cnt, dis, N);
    scan_block_sums<<<nScanBlocks, 256, 0, stream>>>(cnt, partials, N);
    scan_partials<<<1, 256, 0, stream>>>(partials, nScanBlocks, rp, N);
    scan_write<<<nScanBlocks, 256, 0, stream>>>(cnt, partials, rp, cursor, N);
    scatter_edges<<<gE, 256, 0, stream>>>(src, dst, dis, cursor, edata, E);
    build_h0<<<(N * 16 + 255) / 256, 256, 0, stream>>>(x, xm, h0, N);
    wsplit_kernel<<<5 * 16384 / 256, 256, 0, stream>>>(Wh, Wr1, whi, wlo);

    agg16_kernel<<<(N + 15) / 16, 256, 0, stream>>>(h0, rp, edata, dis, agg16out, N);

    if (fit) {
        // X = fp16 in ws: all intermediate traffic off d_out
        gemm_kernel<16, 1><<<gRows, 256, 0, stream>>>(agg16out, W0, b0, xbuf_ws, N);
        for (int l = 0; l < 4; ++l) {
            agg128split_kernel<true><<<(N + 7) / 8, 256, 0, stream>>>(
                xbuf_ws, rp, edata, dis, ahb, alb, N);
            const unsigned short* wh_l = whi + (size_t)l * 16384;
            const unsigned short* wl_l = wlo + (size_t)l * 16384;
            if (l < 3)
                mfma_gemm_kernel<true, 1><<<gRows, 256, 0, stream>>>(
                    ahb, alb, wh_l, wl_l, bh + (size_t)l * 128, xbuf_ws, N);
            else
                mfma_gemm_kernel<false, 2><<<gRows, 256, 0, stream>>>(
                    ahb, alb, wh_l, wl_l, bh + (size_t)l * 128, emb_out, N);
        }
    } else {
        // fallback: fp32 X on emb region (R5-proven structure)
        float* hbuf = emb_out;
        gemm_kernel<16, 0><<<gRows, 256, 0, stream>>>(agg16out, W0, b0, hbuf, N);
        for (int l = 0; l < 4; ++l) {
            agg128split_kernel<false><<<(N + 7) / 8, 256, 0, stream>>>(
                hbuf, rp, edata, dis, ahb, alb, N);
            const unsigned short* wh_l = whi + (size_t)l * 16384;
            const unsigned short* wl_l = wlo + (size_t)l * 16384;
            if (l < 3)
                mfma_gemm_kernel<true, 0><<<gRows, 256, 0, stream>>>(
                    ahb, alb, wh_l, wl_l, bh + (size_t)l * 128, hbuf, N);
            else
                mfma_gemm_kernel<false, 2><<<gRows, 256, 0, stream>>>(
                    ahb, alb, wh_l, wl_l, bh + (size_t)l * 128, emb_out, N);
        }
    }

    // head: relu(emb) -> split; fused (Wr1 + relu + Wr2) MFMA kernel -> pred
    relusplit_kernel<<<(N * 128 / 4 + 255) / 256, 256, 0, stream>>>(emb_out, ahb, alb, N * 128);
    mfma_head_kernel<<<gRows, 256, 0, stream>>>(ahb, alb, whi + (size_t)4 * 16384,
                                                wlo + (size_t)4 * 16384, br1, Wr2, br2,
                                                pred_out, N);
}